// Round 6
// baseline (229.210 us; speedup 1.0000x reference)
//
#include <hip/hip_runtime.h>
#include <hip/hip_bf16.h>
#include <math.h>

// Problem constants: B=4, L=96, D=256, H=8, hd=32, FF=1024. M = B*L*L = 36864.
#define M_ROWS 36864

typedef __bf16 bf16x8 __attribute__((ext_vector_type(8)));
typedef float f32x4 __attribute__((ext_vector_type(4)));

__device__ __forceinline__ void gload16(const void* g, void* l) {
  __builtin_amdgcn_global_load_lds((const __attribute__((address_space(1))) void*)g,
                                   (__attribute__((address_space(3))) void*)l, 16, 0, 0);
}

// ---------------- convert table fp32 -> bf16 (8 elems/thread) ----------------
__global__ __launch_bounds__(256) void cvt_bf16_kernel(const float* __restrict__ X,
                                                       __bf16* __restrict__ Y, int n8) {
  int i = blockIdx.x * 256 + threadIdx.x;
  if (i >= n8) return;
  const float4 a = ((const float4*)X)[(size_t)i * 2];
  const float4 b = ((const float4*)X)[(size_t)i * 2 + 1];
  bf16x8 o = {(__bf16)a.x, (__bf16)a.y, (__bf16)a.z, (__bf16)a.w,
              (__bf16)b.x, (__bf16)b.y, (__bf16)b.z, (__bf16)b.w};
  *(bf16x8*)&Y[(size_t)i * 8] = o;
}

// ---------------- pack + transpose weights to bf16 B^T [N,K] ----------------
__global__ __launch_bounds__(256) void pack_w_kernel(
    const float* __restrict__ Wq, const float* __restrict__ Wk, const float* __restrict__ Wv,
    const float* __restrict__ Wo, const float* __restrict__ W1, const float* __restrict__ W2,
    const float* __restrict__ bq, const float* __restrict__ bk, const float* __restrict__ bv,
    __bf16* __restrict__ Wqkv_t, __bf16* __restrict__ Wo_t,
    __bf16* __restrict__ W1_t, __bf16* __restrict__ W2_t, float* __restrict__ bqkv) {
  int idx = blockIdx.x * 256 + threadIdx.x;
  const int S1 = 768 * 256, S2 = 256 * 256, S3 = 1024 * 256;
  if (idx < S1) {
    int n = idx / 256, k = idx % 256;
    int sel = n >> 8, nn = n & 255;
    const float* W = (sel == 0) ? Wq : (sel == 1) ? Wk : Wv;
    Wqkv_t[idx] = (__bf16)W[k * 256 + nn];
  } else if (idx < S1 + S2) {
    int j = idx - S1; int n = j / 256, k = j % 256;
    Wo_t[j] = (__bf16)Wo[k * 256 + n];
  } else if (idx < S1 + S2 + S3) {
    int j = idx - S1 - S2; int n = j / 256, k = j % 256;
    W1_t[j] = (__bf16)W1[k * 1024 + n];
  } else {
    int j = idx - S1 - S2 - S3; int n = j / 1024, k = j % 1024;
    W2_t[j] = (__bf16)W2[k * 256 + n];
  }
  if (idx < 768) {
    int sel = idx >> 8, jj = idx & 255;
    const float* bsrc = (sel == 0) ? bq : (sel == 1) ? bk : bv;
    bqkv[idx] = bsrc[jj];
  }
}

// ---------------- unified 8-wave MFMA GEMM: BM=128 x BN=256, BK=32 ------------
// 512 threads, wave grid 2M x 4N, per-wave 64x64 (4x4 frags of 16x16x32).
// 2-phase dbuf; LDS XOR-swizzle via pre-swizzled global source (2-way max).
// EPI: 0 = bias -> bf16, 1 = bias+relu -> bf16,
//      2 = bias + fp32 resid + LayerNorm -> fp32 (+ optional bf16 copy). N must be 256.
template <int EPI, bool EMIT_BF16>
__global__ __launch_bounds__(512) void gemm8_kernel(
    const __bf16* __restrict__ A, const __bf16* __restrict__ Bt,
    const float* __restrict__ bias, const float* __restrict__ resid,
    const float* __restrict__ gamma, const float* __restrict__ beta,
    void* __restrict__ Y, __hip_bfloat16* __restrict__ Yb, int N, int K) {
  __shared__ __bf16 As[2][128 * 32];
  __shared__ __bf16 Bs[2][256 * 32];
  __shared__ float red[2][4][128];   // LN scratch (EPI==2)
  const int tid = threadIdx.x;
  const int lane = tid & 63, wv = tid >> 6;
  const int wm = wv >> 2, wn = wv & 3;
  // XCD-chunked block swizzle (nwg divisible by 8 for all our grids)
  const int gx = gridDim.x;
  const int nwg = gx * gridDim.y;
  int lin = blockIdx.y * gx + blockIdx.x;
  lin = (lin & 7) * (nwg >> 3) + (lin >> 3);
  const int n0 = (lin % gx) * 256;
  const int m0 = (lin / gx) * 128;
  const int fr = lane & 15, g = lane >> 4;
  const int arow = tid >> 2;                             // 0..127
  const int gcol = ((tid & 3) ^ ((tid >> 3) & 3)) * 8;   // pre-swizzled source colseg

  f32x4 acc[4][4] = {};
  const int nph = K >> 5;

#define STAGE8(buf, kb)                                                   \
  {                                                                       \
    gload16(A + (size_t)(m0 + arow) * K + (kb) + gcol,                    \
            &As[buf][wv * 512]);                                          \
    gload16(Bt + (size_t)(n0 + arow) * K + (kb) + gcol,                   \
            &Bs[buf][wv * 512]);                                          \
    gload16(Bt + (size_t)(n0 + 128 + arow) * K + (kb) + gcol,             \
            &Bs[buf][4096 + wv * 512]);                                   \
  }

  STAGE8(0, 0)
  __syncthreads();
  int cur = 0;
  for (int p = 0; p < nph; ++p) {
    if (p + 1 < nph) STAGE8(cur ^ 1, (p + 1) * 32)   // next tile flies over compute
    const int cs = (g ^ ((fr >> 1) & 3)) * 8;        // read-side un-swizzle
    bf16x8 av[4], bv[4];
#pragma unroll
    for (int mi = 0; mi < 4; ++mi)
      av[mi] = *reinterpret_cast<const bf16x8*>(&As[cur][(wm * 64 + mi * 16 + fr) * 32 + cs]);
#pragma unroll
    for (int ni = 0; ni < 4; ++ni)
      bv[ni] = *reinterpret_cast<const bf16x8*>(&Bs[cur][(wn * 64 + ni * 16 + fr) * 32 + cs]);
#pragma unroll
    for (int mi = 0; mi < 4; ++mi)
#pragma unroll
      for (int ni = 0; ni < 4; ++ni)
        acc[mi][ni] = __builtin_amdgcn_mfma_f32_16x16x32_bf16(av[mi], bv[ni], acc[mi][ni], 0, 0, 0);
    __syncthreads();   // all reads of cur done + next tile staged (vmcnt drain)
    cur ^= 1;
  }
#undef STAGE8

  if (EPI < 2) {
    // ---- plain epilogue: bias (+relu), bf16 out ----
    const int crow = m0 + wm * 64 + g * 4;
    const int ccol = n0 + wn * 64 + fr;
    __hip_bfloat16* ob = (__hip_bfloat16*)Y;
#pragma unroll
    for (int mi = 0; mi < 4; ++mi) {
#pragma unroll
      for (int ni = 0; ni < 4; ++ni) {
        const int col = ccol + ni * 16;
        const float bb = bias[col];
#pragma unroll
        for (int r = 0; r < 4; ++r) {
          const int row = crow + mi * 16 + r;
          float v = acc[mi][ni][r] + bb;
          if (EPI == 1) v = fmaxf(v, 0.f);
          ob[(size_t)row * N + col] = __float2bfloat16(v);
        }
      }
    }
  } else {
    // ---- LN epilogue: v = acc + bias + resid; LayerNorm over 256 cols ----
    float* Yf = (float*)Y;
    const int colb = wn * 64 + fr;  // + ni*16
    float bb[4], gg[4], be[4];
#pragma unroll
    for (int ni = 0; ni < 4; ++ni) {
      bb[ni] = bias[colb + ni * 16];
      gg[ni] = gamma[colb + ni * 16];
      be[ni] = beta[colb + ni * 16];
    }
#pragma unroll
    for (int mi = 0; mi < 4; ++mi) {
#pragma unroll
      for (int r = 0; r < 4; ++r) {
        const int lr = wm * 64 + mi * 16 + g * 4 + r;
        const size_t grow = (size_t)(m0 + lr) * 256;
        float s = 0.f, q = 0.f;
#pragma unroll
        for (int ni = 0; ni < 4; ++ni) {
          float v = acc[mi][ni][r] + bb[ni] + resid[grow + colb + ni * 16];
          acc[mi][ni][r] = v;
          s += v; q += v * v;
        }
#pragma unroll
        for (int o = 8; o > 0; o >>= 1) { s += __shfl_xor(s, o); q += __shfl_xor(q, o); }
        if (fr == 0) { red[0][wn][lr] = s; red[1][wn][lr] = q; }
      }
    }
    __syncthreads();
#pragma unroll
    for (int mi = 0; mi < 4; ++mi) {
#pragma unroll
      for (int r = 0; r < 4; ++r) {
        const int lr = wm * 64 + mi * 16 + g * 4 + r;
        const size_t grow = (size_t)(m0 + lr) * 256;
        const float s = red[0][0][lr] + red[0][1][lr] + red[0][2][lr] + red[0][3][lr];
        const float q = red[1][0][lr] + red[1][1][lr] + red[1][2][lr] + red[1][3][lr];
        const float mean = s * (1.0f / 256.0f);
        const float var = q * (1.0f / 256.0f) - mean * mean;
        const float inv = rsqrtf(var + 1e-5f);
#pragma unroll
        for (int ni = 0; ni < 4; ++ni) {
          const float y = (acc[mi][ni][r] - mean) * inv * gg[ni] + be[ni];
          Yf[grow + colb + ni * 16] = y;
          if (EMIT_BF16) Yb[grow + colb + ni * 16] = __float2bfloat16(y);
        }
      }
    }
  }
}

// ---------------- MFMA attention: one block per (b,h,x), 6 waves ----------------
__global__ __launch_bounds__(384) void attn_mfma_kernel(
    const __bf16* __restrict__ qkv, const float* __restrict__ depm,
    const float* __restrict__ Wdep, const float* __restrict__ bdep,
    __hip_bfloat16* __restrict__ ctx) {
  __shared__ __bf16 Qs[96][40];
  __shared__ __bf16 Ks[96][40];
  __shared__ __bf16 Vt[32][104];
  __shared__ __bf16 Ps[6][16][104];
  // XCD swizzle: 8 heads of one (b,x) slab -> consecutive -> same XCD L2
  int lin = blockIdx.x;
  lin = (lin & 7) * 384 + (lin >> 3);
  const int h = lin & 7;
  const int sx = lin >> 3;
  const int x = sx % 96;
  const int b = sx / 96;
  const int tid = threadIdx.x;
  const size_t slab = (size_t)(b * 96 + x) * 96;
  const size_t base = slab * 768 + h * 32;
#pragma unroll
  for (int t = 0; t < 3; ++t) {
    const int idx = tid + t * 384;
    const int r = idx / 12, rem = idx % 12, mat = rem >> 2, seg = rem & 3;
    const int d0 = seg * 8;
    bf16x8 v8 = *(const bf16x8*)&qkv[base + (size_t)r * 768 + mat * 256 + d0];
    if (mat == 0)      *(bf16x8*)&Qs[r][d0] = v8;
    else if (mat == 1) *(bf16x8*)&Ks[r][d0] = v8;
    else {
#pragma unroll
      for (int e = 0; e < 8; ++e) Vt[d0 + e][r] = v8[e];
    }
  }
  __syncthreads();
  const int wave = tid >> 6, lane = tid & 63;
  const int fr = lane & 15, g = lane >> 4;
  const int q0 = wave * 16;
  const float wd = Wdep[h], bd = bdep[h];
  float depb[6];
#pragma unroll
  for (int f = 0; f < 6; ++f) depb[f] = depm[slab + fr + 16 * f] * wd + bd;
  const bf16x8 av = *(const bf16x8*)&Qs[q0 + fr][g * 8];
  f32x4 sacc[6];
#pragma unroll
  for (int f = 0; f < 6; ++f) {
    const bf16x8 bv = *(const bf16x8*)&Ks[f * 16 + fr][g * 8];
    sacc[f] = __builtin_amdgcn_mfma_f32_16x16x32_bf16(av, bv, (f32x4){0.f, 0.f, 0.f, 0.f}, 0, 0, 0);
  }
  const float scale = 0.17677669529663687f;
  float ev[6][4];
  float inv[4];
#pragma unroll
  for (int r = 0; r < 4; ++r) {
    float m = -1e30f;
#pragma unroll
    for (int f = 0; f < 6; ++f) {
      ev[f][r] = sacc[f][r] * scale + depb[f];
      m = fmaxf(m, ev[f][r]);
    }
#pragma unroll
    for (int o = 8; o > 0; o >>= 1) m = fmaxf(m, __shfl_xor(m, o));
    float sum = 0.f;
#pragma unroll
    for (int f = 0; f < 6; ++f) { ev[f][r] = __expf(ev[f][r] - m); sum += ev[f][r]; }
#pragma unroll
    for (int o = 8; o > 0; o >>= 1) sum += __shfl_xor(sum, o);
    inv[r] = 1.0f / sum;
  }
#pragma unroll
  for (int f = 0; f < 6; ++f)
#pragma unroll
    for (int r = 0; r < 4; ++r)
      Ps[wave][g * 4 + r][fr + 16 * f] = (__bf16)ev[f][r];
  asm volatile("s_waitcnt lgkmcnt(0)" ::: "memory");
  f32x4 o0 = {0.f, 0.f, 0.f, 0.f}, o1 = {0.f, 0.f, 0.f, 0.f};
#pragma unroll
  for (int s = 0; s < 3; ++s) {
    const bf16x8 pa  = *(const bf16x8*)&Ps[wave][fr][s * 32 + g * 8];
    const bf16x8 vb0 = *(const bf16x8*)&Vt[fr][s * 32 + g * 8];
    const bf16x8 vb1 = *(const bf16x8*)&Vt[16 + fr][s * 32 + g * 8];
    o0 = __builtin_amdgcn_mfma_f32_16x16x32_bf16(pa, vb0, o0, 0, 0, 0);
    o1 = __builtin_amdgcn_mfma_f32_16x16x32_bf16(pa, vb1, o1, 0, 0, 0);
  }
  const size_t orow = (slab + q0 + g * 4) * 256 + h * 32;
#pragma unroll
  for (int r = 0; r < 4; ++r) {
    ctx[orow + (size_t)r * 256 + fr]      = __float2bfloat16(o0[r] * inv[r]);
    ctx[orow + (size_t)r * 256 + 16 + fr] = __float2bfloat16(o1[r] * inv[r]);
  }
}

extern "C" void kernel_launch(void* const* d_in, const int* in_sizes, int n_in,
                              void* d_out, int out_size, void* d_ws, size_t ws_size,
                              hipStream_t stream) {
  (void)in_sizes; (void)n_in; (void)out_size; (void)ws_size;
  const float* table = (const float*)d_in[0];
  const float* depm  = (const float*)d_in[1];
  const float* Wq = (const float*)d_in[2];   const float* bq = (const float*)d_in[3];
  const float* Wk = (const float*)d_in[4];   const float* bk = (const float*)d_in[5];
  const float* Wv = (const float*)d_in[6];   const float* bv = (const float*)d_in[7];
  const float* Wo = (const float*)d_in[8];   const float* bo = (const float*)d_in[9];
  const float* Wdep = (const float*)d_in[10]; const float* bdep = (const float*)d_in[11];
  const float* g1 = (const float*)d_in[12];  const float* be1 = (const float*)d_in[13];
  const float* W1 = (const float*)d_in[14];  const float* b1 = (const float*)d_in[15];
  const float* W2 = (const float*)d_in[16];  const float* b2 = (const float*)d_in[17];
  const float* g2 = (const float*)d_in[18];  const float* be2 = (const float*)d_in[19];

  char* ws = (char*)d_ws;
  size_t off = 0;
  __bf16* qkvb  = (__bf16*)(ws + off); off += (size_t)M_ROWS * 768 * 2;
  __bf16* ctxb  = (__bf16*)(ws + off); off += (size_t)M_ROWS * 256 * 2;
  float*  outb  = (float*) (ws + off); off += (size_t)M_ROWS * 256 * 4;
  __bf16* outbb = (__bf16*)(ws + off); off += (size_t)M_ROWS * 256 * 2;
  __bf16* hidb  = (__bf16*)(ws + off); off += (size_t)M_ROWS * 1024 * 2;
  __bf16* tabb  = (__bf16*)(ws + off); off += (size_t)M_ROWS * 256 * 2;
  __bf16* Wqkv_t = (__bf16*)(ws + off); off += 768 * 256 * 2;
  __bf16* Wo_t   = (__bf16*)(ws + off); off += 256 * 256 * 2;
  __bf16* W1_t   = (__bf16*)(ws + off); off += 1024 * 256 * 2;
  __bf16* W2_t   = (__bf16*)(ws + off); off += 256 * 1024 * 2;
  float*  bqkv   = (float*)(ws + off);

  cvt_bf16_kernel<<<4608, 256, 0, stream>>>(table, tabb, M_ROWS * 256 / 8);
  pack_w_kernel<<<3072, 256, 0, stream>>>(Wq, Wk, Wv, Wo, W1, W2, bq, bk, bv,
                                          Wqkv_t, Wo_t, W1_t, W2_t, bqkv);
  // qkv = table @ Wqkv + bqkv -> bf16 [M,768]
  gemm8_kernel<0, false><<<dim3(3, 288), 512, 0, stream>>>(
      tabb, Wqkv_t, bqkv, nullptr, nullptr, nullptr, qkvb, nullptr, 768, 256);
  // attention -> ctx bf16 [M,256]
  attn_mfma_kernel<<<3072, 384, 0, stream>>>(qkvb, depm, Wdep, bdep, (__hip_bfloat16*)ctxb);
  // outb/outbb = LN1(ctx @ Wo + bo + table)  [fused]
  gemm8_kernel<2, true><<<dim3(1, 288), 512, 0, stream>>>(
      ctxb, Wo_t, bo, table, g1, be1, outb, (__hip_bfloat16*)outbb, 256, 256);
  // hidden = relu(outbb @ W1 + b1) -> bf16 [M,1024]
  gemm8_kernel<1, false><<<dim3(4, 288), 512, 0, stream>>>(
      outbb, W1_t, b1, nullptr, nullptr, nullptr, hidb, nullptr, 1024, 256);
  // d_out = LN2(hidden @ W2 + b2 + outb)  [fused]
  gemm8_kernel<2, false><<<dim3(1, 288), 512, 0, stream>>>(
      hidb, W2_t, b2, outb, g2, be2, (float*)d_out, nullptr, 256, 1024);
}